// Round 5
// baseline (2764.931 us; speedup 1.0000x reference)
//
#include <hip/hip_runtime.h>
#include <hip/hip_fp16.h>
#include <cmath>

#define Nn   100000
#define Ee   1600000
#define FIN  256
#define Hh   128
#define EDIMM 16
#define NL   3
#define NOUT 64

typedef _Float16 f16x8 __attribute__((ext_vector_type(8)));
typedef float f32x4 __attribute__((ext_vector_type(4)));

static __device__ __forceinline__ unsigned int h22u(__half2 h) {
  union { unsigned int u; __half2 h; } c; c.h = h; return c.u;
}

// ---------------- in_proj: h = x @ in_w + in_b  [N,256]@[256,128] ----------------
__global__ __launch_bounds__(128) void in_proj_kernel(const float* __restrict__ x,
    const float* __restrict__ w, const float* __restrict__ b, float* __restrict__ h) {
  __shared__ float xs[8][FIN];
  int r0 = blockIdx.x * 8;
  for (int i = threadIdx.x; i < 8 * FIN; i += 128) {
    int r = i >> 8, c = i & (FIN - 1);
    int rr = r0 + r;
    xs[r][c] = (rr < Nn) ? x[rr * FIN + c] : 0.f;
  }
  __syncthreads();
  int t = threadIdx.x;
  float acc[8] = {};
  for (int kk = 0; kk < FIN; kk++) {
    float wv = w[kk * Hh + t];
#pragma unroll
    for (int r = 0; r < 8; r++) acc[r] += xs[r][kk] * wv;
  }
  float bias = b[t];
#pragma unroll
  for (int r = 0; r < 8; r++) {
    int rr = r0 + r;
    if (rr < Nn) h[rr * Hh + t] = acc[r] + bias;
  }
}

// ---- fused k,q,v,skip: 4x [N,128]@[128,128]; k fp16, q/v interleaved fp16, skip fp32 ----
__global__ __launch_bounds__(128) void kqvs_kernel(const float* __restrict__ h,
    const float* __restrict__ Wk, const float* __restrict__ bk,
    const float* __restrict__ Wq, const float* __restrict__ bq,
    const float* __restrict__ Wv, const float* __restrict__ bv,
    const float* __restrict__ Ws, const float* __restrict__ bs,
    __half* __restrict__ kout, __half* __restrict__ qvb, float* __restrict__ hnew) {
  __shared__ float hs[8][Hh];
  int r0 = blockIdx.x * 8;
  for (int i = threadIdx.x; i < 8 * Hh; i += 128) {
    int r = i >> 7, c = i & 127;
    int rr = r0 + r;
    hs[r][c] = (rr < Nn) ? h[rr * Hh + c] : 0.f;
  }
  __syncthreads();
  int t = threadIdx.x;
  float ak[8] = {}, aq[8] = {}, av[8] = {}, as_[8] = {};
  for (int kk = 0; kk < Hh; kk++) {
    float wk = Wk[kk * Hh + t];
    float wq = Wq[kk * Hh + t];
    float wv = Wv[kk * Hh + t];
    float ws = Ws[kk * Hh + t];
#pragma unroll
    for (int r = 0; r < 8; r++) {
      float hv = hs[r][kk];
      ak[r] += hv * wk;
      aq[r] += hv * wq;
      av[r] += hv * wv;
      as_[r] += hv * ws;
    }
  }
  float bkv = bk[t], bqv = bq[t], bvv = bv[t], bsv = bs[t];
#pragma unroll
  for (int r = 0; r < 8; r++) {
    int rr = r0 + r;
    if (rr < Nn) {
      kout[rr * Hh + t] = __float2half(ak[r] + bkv);
      qvb[(size_t)rr * 256 + t]       = __float2half(aq[r] + bqv);
      qvb[(size_t)rr * 256 + 128 + t] = __float2half(av[r] + bvv);
      hnew[rr * Hh + t] = as_[r] + bsv;
    }
  }
}

// ---------------- CSR build ----------------
__global__ __launch_bounds__(256) void zero_kernel(int* __restrict__ p, int n) {
  int i = blockIdx.x * 256 + threadIdx.x;
  if (i < n) p[i] = 0;
}

__global__ __launch_bounds__(256) void hist_kernel(const int* __restrict__ ei_dst,
                                                   int* __restrict__ counts) {
  int e = blockIdx.x * 256 + threadIdx.x;
  if (e < Ee) atomicAdd(&counts[ei_dst[e]], 1);
}

__global__ __launch_bounds__(256) void scan_block_kernel(const int* __restrict__ counts,
    int* __restrict__ rowptr, int* __restrict__ bsums) {
  __shared__ int tsums[256];
  int b = blockIdx.x, t = threadIdx.x;
  int base = b * 1024 + t * 4;
  int v[4]; int s = 0;
#pragma unroll
  for (int j = 0; j < 4; j++) {
    int idx = base + j;
    v[j] = (idx < Nn) ? counts[idx] : 0;
    s += v[j];
  }
  tsums[t] = s;
  __syncthreads();
  for (int off = 1; off < 256; off <<= 1) {
    int y = (t >= off) ? tsums[t - off] : 0;
    __syncthreads();
    tsums[t] += y;
    __syncthreads();
  }
  int excl = tsums[t] - s;
#pragma unroll
  for (int j = 0; j < 4; j++) {
    int idx = base + j;
    if (idx < Nn) rowptr[idx] = excl;
    excl += v[j];
  }
  if (t == 255) bsums[b] = tsums[255];
}

__global__ __launch_bounds__(128) void scan_sums_kernel(int* __restrict__ bsums, int nb) {
  __shared__ int sh[128];
  int t = threadIdx.x;
  int v = (t < nb) ? bsums[t] : 0;
  sh[t] = v;
  __syncthreads();
  for (int off = 1; off < 128; off <<= 1) {
    int y = (t >= off) ? sh[t - off] : 0;
    __syncthreads();
    sh[t] += y;
    __syncthreads();
  }
  if (t < nb) bsums[t] = sh[t] - v;
}

__global__ __launch_bounds__(256) void finalize_rowptr_kernel(int* __restrict__ rowptr,
    const int* __restrict__ bsums, int* __restrict__ cursor) {
  int i = blockIdx.x * 256 + threadIdx.x;
  if (i < Nn) {
    int r = rowptr[i] + bsums[i >> 10];
    rowptr[i] = r;
    cursor[i] = r;
  }
  if (i == Nn) rowptr[Nn] = Ee;
}

// permute: src_perm (int), eaH = fp16 [E][16] in CSR order (32 B/edge)
__global__ __launch_bounds__(256) void fill_perm_kernel(const int* __restrict__ ei_src,
    const int* __restrict__ ei_dst, const float* __restrict__ ea,
    int* __restrict__ cursor, int* __restrict__ src_perm, __half* __restrict__ eaH) {
  int e = blockIdx.x * 256 + threadIdx.x;
  if (e < Ee) {
    int d = ei_dst[e];
    int slot = atomicAdd(&cursor[d], 1);
    src_perm[slot] = ei_src[e];
    const float4* s = (const float4*)(ea + (size_t)e * EDIMM);
    float4 f0 = s[0], f1 = s[1], f2 = s[2], f3 = s[3];
    uint4 u0, u1;
    u0.x = h22u(__floats2half2_rn(f0.x, f0.y)); u0.y = h22u(__floats2half2_rn(f0.z, f0.w));
    u0.z = h22u(__floats2half2_rn(f1.x, f1.y)); u0.w = h22u(__floats2half2_rn(f1.z, f1.w));
    u1.x = h22u(__floats2half2_rn(f2.x, f2.y)); u1.y = h22u(__floats2half2_rn(f2.z, f2.w));
    u1.z = h22u(__floats2half2_rn(f3.x, f3.y)); u1.w = h22u(__floats2half2_rn(f3.z, f3.w));
    uint4* dp = (uint4*)(eaH + (size_t)slot * EDIMM);
    dp[0] = u0; dp[1] = u1;
  }
}

// pack We^T into MFMA A-fragments: frag[layer][t][lane][j] = We[k=8*quad+j][16t+col], 0 for k>=16
__global__ __launch_bounds__(64) void weT_frag_kernel(const float* __restrict__ We,
                                                      __half* __restrict__ frag) {
  int l = threadIdx.x, layer = blockIdx.x;
  int quad = l >> 4, col = l & 15;
  const float* W = We + (size_t)layer * EDIMM * Hh;
  __half* out = frag + (size_t)layer * 8 * 64 * 8;
  for (int t = 0; t < 8; t++) {
#pragma unroll
    for (int j = 0; j < 8; j++) {
      int k = 8 * quad + j;
      float v = (k < EDIMM) ? W[k * Hh + 16 * t + col] : 0.f;
      out[((size_t)t * 64 + l) * 8 + j] = __float2half(v);
    }
  }
}

// ---- MFMA edge kernel: one wave per dst row, 16 edges/batch ----
// D[ch][edge] = We^T(128x16) . ea^T(16x16) via 8x mfma_f32_16x16x32_f16 (K padded).
// Lane (quad,col): edge = col, channels = 16t + 4*quad + i.
__global__ __launch_bounds__(256) void edge_mfma_kernel(
    const __half* __restrict__ kb, const __half* __restrict__ qvb,
    const int* __restrict__ src_perm, const __half* __restrict__ eaH,
    const int* __restrict__ rowptr, const __half* __restrict__ weTfrag_l,
    const float* __restrict__ be_l,
    const float* __restrict__ ln_g_l, const float* __restrict__ ln_b_l,
    float* __restrict__ hbuf) {
  int wave = threadIdx.x >> 6;
  int lane = threadIdx.x & 63;
  int quad = lane >> 4, col = lane & 15;
  int row = blockIdx.x * 4 + wave;     // grid 25000*4 = 100000 exactly

  // A fragments (layer-constant), 16B/lane per tile, coalesced
  f16x8 afrag[8];
  {
    const uint4* fp = (const uint4*)weTfrag_l;
#pragma unroll
    for (int t = 0; t < 8; t++) {
      union { uint4 u; f16x8 h; } c;
      c.u = fp[t * 64 + lane];
      afrag[t] = c.h;
    }
  }
  // k[row] + be for my channels (tile t -> cb = 16t + 4*quad)
  float kpb[8][4];
#pragma unroll
  for (int t = 0; t < 8; t++) {
    int cb = 16 * t + 4 * quad;
    __half2 k0 = *(const __half2*)(kb + (size_t)row * Hh + cb);
    __half2 k1 = *(const __half2*)(kb + (size_t)row * Hh + cb + 2);
    float4 bv = *(const float4*)(be_l + cb);
    kpb[t][0] = __half2float(k0.x) + bv.x;
    kpb[t][1] = __half2float(k0.y) + bv.y;
    kpb[t][2] = __half2float(k1.x) + bv.z;
    kpb[t][3] = __half2float(k1.y) + bv.w;
  }

  f32x4 zero4 = {0.f, 0.f, 0.f, 0.f};
  float agg[8][4] = {};
  int beg = rowptr[row], end = rowptr[row + 1];

  for (int base = beg; base < end; base += 16) {
    int my_e = base + col;
    bool valid = my_e < end;
    int ce = valid ? my_e : end - 1;
    int src = src_perm[ce];
    // B fragment: ea^T column = my edge; k = 8*quad+j, zero for k>=16
    uint4 bu = make_uint4(0, 0, 0, 0);
    if (quad < 2) bu = *(const uint4*)(eaH + (size_t)ce * EDIMM + quad * 8);
    union { uint4 u; f16x8 h; } bc; bc.u = bu;
    f16x8 bfrag = bc.h;

    const __half* qp = qvb + (size_t)src * 256 + 4 * quad;
#pragma unroll
    for (int t = 0; t < 8; t++) {
      f32x4 emb = __builtin_amdgcn_mfma_f32_16x16x32_f16(afrag[t], bfrag, zero4, 0, 0, 0);
      __half2 q0 = *(const __half2*)(qp + 16 * t);
      __half2 q1 = *(const __half2*)(qp + 16 * t + 2);
      __half2 v0 = *(const __half2*)(qp + 16 * t + 128);
      __half2 v1 = *(const __half2*)(qp + 16 * t + 130);
      if (valid) {
        float qf[4] = { __half2float(q0.x), __half2float(q0.y),
                        __half2float(q1.x), __half2float(q1.y) };
        float vf[4] = { __half2float(v0.x), __half2float(v0.y),
                        __half2float(v1.x), __half2float(v1.y) };
#pragma unroll
        for (int i = 0; i < 4; i++) {
          float p = kpb[t][i] + emb[i] + qf[i];
          float g = 1.f / (1.f + __expf(-p));
          agg[t][i] += g * vf[i];
        }
      }
    }
  }

  // reduce over the 16 edge-lanes (same quad group)
#pragma unroll
  for (int t = 0; t < 8; t++) {
#pragma unroll
    for (int i = 0; i < 4; i++) {
      float s = agg[t][i];
      s += __shfl_xor(s, 1);
      s += __shfl_xor(s, 2);
      s += __shfl_xor(s, 4);
      s += __shfl_xor(s, 8);
      agg[t][i] = s;
    }
  }

  // skip + LayerNorm + GELU
  float y[8][4];
  float s = 0.f;
#pragma unroll
  for (int t = 0; t < 8; t++) {
    int cb = 16 * t + 4 * quad;
    float4 hv = *(const float4*)(hbuf + (size_t)row * Hh + cb);
    y[t][0] = hv.x + agg[t][0];
    y[t][1] = hv.y + agg[t][1];
    y[t][2] = hv.z + agg[t][2];
    y[t][3] = hv.w + agg[t][3];
    s += y[t][0] + y[t][1] + y[t][2] + y[t][3];
  }
  s += __shfl_xor(s, 16);
  s += __shfl_xor(s, 32);
  float mu = s * (1.f / 128.f);
  float vv = 0.f;
#pragma unroll
  for (int t = 0; t < 8; t++) {
#pragma unroll
    for (int i = 0; i < 4; i++) {
      float d = y[t][i] - mu;
      vv += d * d;
    }
  }
  vv += __shfl_xor(vv, 16);
  vv += __shfl_xor(vv, 32);
  float rstd = rsqrtf(vv * (1.f / 128.f) + 1e-5f);
#pragma unroll
  for (int t = 0; t < 8; t++) {
    int cb = 16 * t + 4 * quad;
    float4 lg = *(const float4*)(ln_g_l + cb);
    float4 lb = *(const float4*)(ln_b_l + cb);
    float o[4];
    o[0] = (y[t][0] - mu) * rstd * lg.x + lb.x;
    o[1] = (y[t][1] - mu) * rstd * lg.y + lb.y;
    o[2] = (y[t][2] - mu) * rstd * lg.z + lb.z;
    o[3] = (y[t][3] - mu) * rstd * lg.w + lb.w;
#pragma unroll
    for (int i = 0; i < 4; i++)
      o[i] = 0.5f * o[i] * (1.f + erff(o[i] * 0.70710678118654752f));
    if (col == t) {
      float4 ov = make_float4(o[0], o[1], o[2], o[3]);
      *(float4*)(hbuf + (size_t)row * Hh + cb) = ov;
    }
  }
}

// ---- out_proj: out = h @ out_w  [N,128]@[128,64] ----
__global__ __launch_bounds__(64) void out_proj_kernel(const float* __restrict__ h,
    const float* __restrict__ w, float* __restrict__ out) {
  __shared__ float hs[16][Hh];
  int r0 = blockIdx.x * 16;
  for (int i = threadIdx.x; i < 16 * Hh; i += 64) {
    int r = i >> 7, c = i & 127;
    int rr = r0 + r;
    hs[r][c] = (rr < Nn) ? h[rr * Hh + c] : 0.f;
  }
  __syncthreads();
  int t = threadIdx.x;
  float acc[16] = {};
  for (int kk = 0; kk < Hh; kk++) {
    float wv = w[kk * NOUT + t];
#pragma unroll
    for (int r = 0; r < 16; r++) acc[r] += hs[r][kk] * wv;
  }
#pragma unroll
  for (int r = 0; r < 16; r++) {
    int rr = r0 + r;
    if (rr < Nn) out[rr * NOUT + t] = acc[r];
  }
}

extern "C" void kernel_launch(void* const* d_in, const int* in_sizes, int n_in,
                              void* d_out, int out_size, void* d_ws, size_t ws_size,
                              hipStream_t stream) {
  const float* x    = (const float*)d_in[0];
  const int*   ei   = (const int*)d_in[1];
  const float* ea   = (const float*)d_in[2];
  const float* in_w = (const float*)d_in[3];
  const float* in_b = (const float*)d_in[4];
  const float* Wk   = (const float*)d_in[5];
  const float* bk   = (const float*)d_in[6];
  const float* Wq   = (const float*)d_in[7];
  const float* bq   = (const float*)d_in[8];
  const float* Wv   = (const float*)d_in[9];
  const float* bv   = (const float*)d_in[10];
  const float* We   = (const float*)d_in[11];
  const float* be   = (const float*)d_in[12];
  const float* Ws   = (const float*)d_in[13];
  const float* bs   = (const float*)d_in[14];
  const float* ln_g = (const float*)d_in[15];
  const float* ln_b = (const float*)d_in[16];
  const float* out_w = (const float*)d_in[17];
  float* out = (float*)d_out;

  const int* ei_src = ei;
  const int* ei_dst = ei + Ee;

  size_t NH = (size_t)Nn * Hh;
  char* wsp = (char*)d_ws;
  float*  hA = (float*)wsp;           wsp += NH * 4;
  float*  hB = (float*)wsp;           wsp += NH * 4;
  __half* kb = (__half*)wsp;          wsp += NH * 2;
  __half* qvb = (__half*)wsp;         wsp += NH * 2 * 2;   // [N,256] interleaved q|v
  int* rowptr = (int*)wsp;            wsp += (Nn + 1) * 4;
  int* cursor = (int*)wsp;            wsp += Nn * 4;
  int* bsums  = (int*)wsp;            wsp += 128 * 4;
  int* src_perm = (int*)wsp;          wsp += (size_t)Ee * 4;
  __half* eaH = (__half*)wsp;         wsp += (size_t)Ee * EDIMM * 2;
  __half* weTfrag = (__half*)wsp;     wsp += (size_t)NL * 8 * 64 * 8 * 2;

  const int NB_SCAN = (Nn + 1023) / 1024;   // 98

  zero_kernel<<<(Nn + 255) / 256, 256, 0, stream>>>(cursor, Nn);
  hist_kernel<<<(Ee + 255) / 256, 256, 0, stream>>>(ei_dst, cursor);
  scan_block_kernel<<<NB_SCAN, 256, 0, stream>>>(cursor, rowptr, bsums);
  scan_sums_kernel<<<1, 128, 0, stream>>>(bsums, NB_SCAN);
  finalize_rowptr_kernel<<<(Nn + 1 + 255) / 256, 256, 0, stream>>>(rowptr, bsums, cursor);
  fill_perm_kernel<<<(Ee + 255) / 256, 256, 0, stream>>>(ei_src, ei_dst, ea, cursor,
                                                         src_perm, eaH);
  weT_frag_kernel<<<NL, 64, 0, stream>>>(We, weTfrag);

  in_proj_kernel<<<(Nn + 7) / 8, 128, 0, stream>>>(x, in_w, in_b, hA);

  float* h  = hA;
  float* hn = hB;
  for (int l = 0; l < NL; l++) {
    kqvs_kernel<<<(Nn + 7) / 8, 128, 0, stream>>>(h,
        Wk + l * Hh * Hh, bk + l * Hh,
        Wq + l * Hh * Hh, bq + l * Hh,
        Wv + l * Hh * Hh, bv + l * Hh,
        Ws + l * Hh * Hh, bs + l * Hh,
        kb, qvb, hn);
    edge_mfma_kernel<<<Nn / 4, 256, 0, stream>>>(kb, qvb, src_perm, eaH,
        rowptr, weTfrag + (size_t)l * 8 * 64 * 8, be + l * Hh,
        ln_g + l * Hh, ln_b + l * Hh, hn);
    float* tmp = h; h = hn; hn = tmp;
  }

  out_proj_kernel<<<(Nn + 15) / 16, 64, 0, stream>>>(h, out_w, out);
}

// Round 6
// 2234.076 us; speedup vs baseline: 1.2376x; 1.2376x over previous
//
#include <hip/hip_runtime.h>
#include <hip/hip_fp16.h>
#include <cmath>

#define Nn   100000
#define Ee   1600000
#define FIN  256
#define Hh   128
#define EDIMM 16
#define NL   3
#define NOUT 64

static __device__ __forceinline__ __half2 u2h2(unsigned int u) {
  union { unsigned int u; __half2 h; } c; c.u = u; return c.h;
}
static __device__ __forceinline__ unsigned int h22u(__half2 h) {
  union { unsigned int u; __half2 h; } c; c.h = h; return c.u;
}

// ---------------- in_proj: h = x @ in_w + in_b  [N,256]@[256,128] ----------------
__global__ __launch_bounds__(128) void in_proj_kernel(const float* __restrict__ x,
    const float* __restrict__ w, const float* __restrict__ b, float* __restrict__ h) {
  __shared__ float xs[8][FIN];
  int r0 = blockIdx.x * 8;
  for (int i = threadIdx.x; i < 8 * FIN; i += 128) {
    int r = i >> 8, c = i & (FIN - 1);
    int rr = r0 + r;
    xs[r][c] = (rr < Nn) ? x[rr * FIN + c] : 0.f;
  }
  __syncthreads();
  int t = threadIdx.x;
  float acc[8] = {};
  for (int kk = 0; kk < FIN; kk++) {
    float wv = w[kk * Hh + t];
#pragma unroll
    for (int r = 0; r < 8; r++) acc[r] += xs[r][kk] * wv;
  }
  float bias = b[t];
#pragma unroll
  for (int r = 0; r < 8; r++) {
    int rr = r0 + r;
    if (rr < Nn) h[rr * Hh + t] = acc[r] + bias;
  }
}

// ---- fused k,q,v,skip: 4x [N,128]@[128,128]; k fp16, q/v interleaved fp16, skip fp32 ----
__global__ __launch_bounds__(128) void kqvs_kernel(const float* __restrict__ h,
    const float* __restrict__ Wk, const float* __restrict__ bk,
    const float* __restrict__ Wq, const float* __restrict__ bq,
    const float* __restrict__ Wv, const float* __restrict__ bv,
    const float* __restrict__ Ws, const float* __restrict__ bs,
    __half* __restrict__ kout, __half* __restrict__ qvb, float* __restrict__ hnew) {
  __shared__ float hs[8][Hh];
  int r0 = blockIdx.x * 8;
  for (int i = threadIdx.x; i < 8 * Hh; i += 128) {
    int r = i >> 7, c = i & 127;
    int rr = r0 + r;
    hs[r][c] = (rr < Nn) ? h[rr * Hh + c] : 0.f;
  }
  __syncthreads();
  int t = threadIdx.x;
  float ak[8] = {}, aq[8] = {}, av[8] = {}, as_[8] = {};
  for (int kk = 0; kk < Hh; kk++) {
    float wk = Wk[kk * Hh + t];
    float wq = Wq[kk * Hh + t];
    float wv = Wv[kk * Hh + t];
    float ws = Ws[kk * Hh + t];
#pragma unroll
    for (int r = 0; r < 8; r++) {
      float hv = hs[r][kk];
      ak[r] += hv * wk;
      aq[r] += hv * wq;
      av[r] += hv * wv;
      as_[r] += hv * ws;
    }
  }
  float bkv = bk[t], bqv = bq[t], bvv = bv[t], bsv = bs[t];
#pragma unroll
  for (int r = 0; r < 8; r++) {
    int rr = r0 + r;
    if (rr < Nn) {
      kout[rr * Hh + t] = __float2half(ak[r] + bkv);
      qvb[(size_t)rr * 256 + t]       = __float2half(aq[r] + bqv);
      qvb[(size_t)rr * 256 + 128 + t] = __float2half(av[r] + bvv);
      hnew[rr * Hh + t] = as_[r] + bsv;
    }
  }
}

// ---------------- CSR build ----------------
__global__ __launch_bounds__(256) void zero_kernel(int* __restrict__ p, int n) {
  int i = blockIdx.x * 256 + threadIdx.x;
  if (i < n) p[i] = 0;
}

__global__ __launch_bounds__(256) void hist_kernel(const int* __restrict__ ei_dst,
                                                   int* __restrict__ counts) {
  int e = blockIdx.x * 256 + threadIdx.x;
  if (e < Ee) atomicAdd(&counts[ei_dst[e]], 1);
}

__global__ __launch_bounds__(256) void scan_block_kernel(const int* __restrict__ counts,
    int* __restrict__ rowptr, int* __restrict__ bsums) {
  __shared__ int tsums[256];
  int b = blockIdx.x, t = threadIdx.x;
  int base = b * 1024 + t * 4;
  int v[4]; int s = 0;
#pragma unroll
  for (int j = 0; j < 4; j++) {
    int idx = base + j;
    v[j] = (idx < Nn) ? counts[idx] : 0;
    s += v[j];
  }
  tsums[t] = s;
  __syncthreads();
  for (int off = 1; off < 256; off <<= 1) {
    int y = (t >= off) ? tsums[t - off] : 0;
    __syncthreads();
    tsums[t] += y;
    __syncthreads();
  }
  int excl = tsums[t] - s;
#pragma unroll
  for (int j = 0; j < 4; j++) {
    int idx = base + j;
    if (idx < Nn) rowptr[idx] = excl;
    excl += v[j];
  }
  if (t == 255) bsums[b] = tsums[255];
}

__global__ __launch_bounds__(128) void scan_sums_kernel(int* __restrict__ bsums, int nb) {
  __shared__ int sh[128];
  int t = threadIdx.x;
  int v = (t < nb) ? bsums[t] : 0;
  sh[t] = v;
  __syncthreads();
  for (int off = 1; off < 128; off <<= 1) {
    int y = (t >= off) ? sh[t - off] : 0;
    __syncthreads();
    sh[t] += y;
    __syncthreads();
  }
  if (t < nb) bsums[t] = sh[t] - v;
}

__global__ __launch_bounds__(256) void finalize_rowptr_kernel(int* __restrict__ rowptr,
    const int* __restrict__ bsums, int* __restrict__ cursor) {
  int i = blockIdx.x * 256 + threadIdx.x;
  if (i < Nn) {
    int r = rowptr[i] + bsums[i >> 10];
    rowptr[i] = r;
    cursor[i] = r;
  }
  if (i == Nn) rowptr[Nn] = Ee;
}

// permute: src_perm (int), ea_perm = pre-broadcast half2 (16 uints/edge, 64 B)
__global__ __launch_bounds__(256) void fill_perm_kernel(const int* __restrict__ ei_src,
    const int* __restrict__ ei_dst, const float* __restrict__ ea,
    int* __restrict__ cursor, int* __restrict__ src_perm,
    unsigned int* __restrict__ ea_perm) {
  int e = blockIdx.x * 256 + threadIdx.x;
  if (e < Ee) {
    int d = ei_dst[e];
    int slot = atomicAdd(&cursor[d], 1);
    src_perm[slot] = ei_src[e];
    const float4* s = (const float4*)(ea + (size_t)e * EDIMM);
    float4 f[4] = { s[0], s[1], s[2], s[3] };
    unsigned int u[16];
#pragma unroll
    for (int j = 0; j < 4; j++) {
      u[j*4+0] = h22u(__half2half2(__float2half(f[j].x)));
      u[j*4+1] = h22u(__half2half2(__float2half(f[j].y)));
      u[j*4+2] = h22u(__half2half2(__float2half(f[j].z)));
      u[j*4+3] = h22u(__half2half2(__float2half(f[j].w)));
    }
    uint4* dp = (uint4*)(ea_perm + (size_t)slot * EDIMM);
#pragma unroll
    for (int j = 0; j < 4; j++)
      dp[j] = make_uint4(u[j*4+0], u[j*4+1], u[j*4+2], u[j*4+3]);
  }
}

// ---- CSR edge kernel: one wave per dst row, packed-fp16 math ----
// All 4-edge batch loads hoisted before compute; launch_bounds(256,4) -> VGPR cap 128
// so the 13 vmem ops per batch can actually stay in flight.
__global__ __launch_bounds__(256, 4) void edge_csr_kernel(
    const __half* __restrict__ kb, const __half* __restrict__ qvb,
    const int* __restrict__ src_perm, const unsigned int* __restrict__ ea_perm,
    const int* __restrict__ rowptr,
    const float* __restrict__ We_l, const float* __restrict__ be_l,
    const float* __restrict__ ln_g_l, const float* __restrict__ ln_b_l,
    float* __restrict__ hbuf) {
  int wave = threadIdx.x >> 6;
  int lane = threadIdx.x & 63;
  int row = blockIdx.x * 4 + wave;   // grid 25000*4 = 100000 exactly
  int c0 = lane * 2;

  // We columns (2 channels) packed to half2 registers
  __half2 wpk[EDIMM];
#pragma unroll
  for (int d = 0; d < EDIMM; d++) {
    float2 wv = *(const float2*)(We_l + d * Hh + c0);
    wpk[d] = __floats2half2_rn(wv.x, wv.y);
  }
  float2 bef = *(const float2*)(be_l + c0);
  __half2 bev = __floats2half2_rn(bef.x, bef.y);

  __half2 kpk = *(const __half2*)(kb + (size_t)row * Hh + c0);

  float agg0 = 0.f, agg1 = 0.f;
  int beg = rowptr[row], end = rowptr[row + 1];

  auto edge_math = [&](uint4 a0, uint4 a1, __half2 qh, __half2 vh) {
    __half2 acc = bev;
    acc = __hfma2(u2h2(a0.x), wpk[0],  acc);
    acc = __hfma2(u2h2(a0.y), wpk[1],  acc);
    acc = __hfma2(u2h2(a0.z), wpk[2],  acc);
    acc = __hfma2(u2h2(a0.w), wpk[3],  acc);
    acc = __hfma2(u2h2(a1.x), wpk[4],  acc);
    acc = __hfma2(u2h2(a1.y), wpk[5],  acc);
    acc = __hfma2(u2h2(a1.z), wpk[6],  acc);
    acc = __hfma2(u2h2(a1.w), wpk[7],  acc);
    __half2 pre = __hadd2(__hadd2(kpk, qh), acc);
    float p0 = __half2float(__low2half(pre));
    float p1 = __half2float(__high2half(pre));
    float g0 = 1.f / (1.f + __expf(-p0));
    float g1 = 1.f / (1.f + __expf(-p1));
    agg0 += g0 * __half2float(__low2half(vh));
    agg1 += g1 * __half2float(__high2half(vh));
  };
  // second half of the 16 ea values uses wpk[8..15]
  auto edge_math2 = [&](uint4 a2, uint4 a3, uint4 a0, uint4 a1, __half2 qh, __half2 vh) {
    __half2 acc = bev;
    acc = __hfma2(u2h2(a0.x), wpk[0],  acc);
    acc = __hfma2(u2h2(a0.y), wpk[1],  acc);
    acc = __hfma2(u2h2(a0.z), wpk[2],  acc);
    acc = __hfma2(u2h2(a0.w), wpk[3],  acc);
    acc = __hfma2(u2h2(a1.x), wpk[4],  acc);
    acc = __hfma2(u2h2(a1.y), wpk[5],  acc);
    acc = __hfma2(u2h2(a1.z), wpk[6],  acc);
    acc = __hfma2(u2h2(a1.w), wpk[7],  acc);
    acc = __hfma2(u2h2(a2.x), wpk[8],  acc);
    acc = __hfma2(u2h2(a2.y), wpk[9],  acc);
    acc = __hfma2(u2h2(a2.z), wpk[10], acc);
    acc = __hfma2(u2h2(a2.w), wpk[11], acc);
    acc = __hfma2(u2h2(a3.x), wpk[12], acc);
    acc = __hfma2(u2h2(a3.y), wpk[13], acc);
    acc = __hfma2(u2h2(a3.z), wpk[14], acc);
    acc = __hfma2(u2h2(a3.w), wpk[15], acc);
    __half2 pre = __hadd2(__hadd2(kpk, qh), acc);
    float p0 = __half2float(__low2half(pre));
    float p1 = __half2float(__high2half(pre));
    float g0 = 1.f / (1.f + __expf(-p0));
    float g1 = 1.f / (1.f + __expf(-p1));
    agg0 += g0 * __half2float(__low2half(vh));
    agg1 += g1 * __half2float(__high2half(vh));
  };

  int e = beg;
  for (; e + 4 <= end; e += 4) {
    int4 s4 = *(const int4*)(src_perm + e);
    // ---- hoist ALL batch loads before any compute ----
    const uint4* eb = (const uint4*)(ea_perm + (size_t)e * EDIMM);
    uint4 ea0a = eb[0], ea0b = eb[1], ea0c = eb[2], ea0d = eb[3];
    uint4 ea1a = eb[4], ea1b = eb[5], ea1c = eb[6], ea1d = eb[7];
    const __half* p0 = qvb + (size_t)s4.x * 256 + c0;
    const __half* p1 = qvb + (size_t)s4.y * 256 + c0;
    const __half* p2 = qvb + (size_t)s4.z * 256 + c0;
    const __half* p3 = qvb + (size_t)s4.w * 256 + c0;
    __half2 q0 = *(const __half2*)p0, v0 = *(const __half2*)(p0 + 128);
    __half2 q1 = *(const __half2*)p1, v1 = *(const __half2*)(p1 + 128);
    __half2 q2 = *(const __half2*)p2, v2 = *(const __half2*)(p2 + 128);
    __half2 q3 = *(const __half2*)p3, v3 = *(const __half2*)(p3 + 128);
    uint4 ea2a = eb[8],  ea2b = eb[9],  ea2c = eb[10], ea2d = eb[11];
    uint4 ea3a = eb[12], ea3b = eb[13], ea3c = eb[14], ea3d = eb[15];
    // ---- compute ----
    edge_math2(ea0c, ea0d, ea0a, ea0b, q0, v0);
    edge_math2(ea1c, ea1d, ea1a, ea1b, q1, v1);
    edge_math2(ea2c, ea2d, ea2a, ea2b, q2, v2);
    edge_math2(ea3c, ea3d, ea3a, ea3b, q3, v3);
  }
  for (; e < end; e++) {
    int src = src_perm[e];
    const uint4* eb = (const uint4*)(ea_perm + (size_t)e * EDIMM);
    uint4 a0 = eb[0], a1 = eb[1], a2 = eb[2], a3 = eb[3];
    const __half* p = qvb + (size_t)src * 256 + c0;
    edge_math2(a2, a3, a0, a1, *(const __half2*)p, *(const __half2*)(p + 128));
  }

  // skip + LayerNorm + GELU (wave owns full row: 2 channels/lane)
  float2 hv = *(float2*)(hbuf + (size_t)row * Hh + c0);
  float y0 = hv.x + agg0, y1 = hv.y + agg1;
  float s = y0 + y1;
#pragma unroll
  for (int off = 32; off; off >>= 1) s += __shfl_xor(s, off);
  float mu = s * (1.f / 128.f);
  float d0 = y0 - mu, d1 = y1 - mu;
  float vv = d0 * d0 + d1 * d1;
#pragma unroll
  for (int off = 32; off; off >>= 1) vv += __shfl_xor(vv, off);
  float rstd = rsqrtf(vv * (1.f / 128.f) + 1e-5f);
  float2 lg = *(const float2*)(ln_g_l + c0);
  float2 lb = *(const float2*)(ln_b_l + c0);
  float o0 = d0 * rstd * lg.x + lb.x;
  float o1 = d1 * rstd * lg.y + lb.y;
  o0 = 0.5f * o0 * (1.f + erff(o0 * 0.70710678118654752f));
  o1 = 0.5f * o1 * (1.f + erff(o1 * 0.70710678118654752f));
  *(float2*)(hbuf + (size_t)row * Hh + c0) = make_float2(o0, o1);
}

// ---- out_proj: out = h @ out_w  [N,128]@[128,64] ----
__global__ __launch_bounds__(64) void out_proj_kernel(const float* __restrict__ h,
    const float* __restrict__ w, float* __restrict__ out) {
  __shared__ float hs[16][Hh];
  int r0 = blockIdx.x * 16;
  for (int i = threadIdx.x; i < 16 * Hh; i += 64) {
    int r = i >> 7, c = i & 127;
    int rr = r0 + r;
    hs[r][c] = (rr < Nn) ? h[rr * Hh + c] : 0.f;
  }
  __syncthreads();
  int t = threadIdx.x;
  float acc[16] = {};
  for (int kk = 0; kk < Hh; kk++) {
    float wv = w[kk * NOUT + t];
#pragma unroll
    for (int r = 0; r < 16; r++) acc[r] += hs[r][kk] * wv;
  }
#pragma unroll
  for (int r = 0; r < 16; r++) {
    int rr = r0 + r;
    if (rr < Nn) out[rr * NOUT + t] = acc[r];
  }
}

extern "C" void kernel_launch(void* const* d_in, const int* in_sizes, int n_in,
                              void* d_out, int out_size, void* d_ws, size_t ws_size,
                              hipStream_t stream) {
  const float* x    = (const float*)d_in[0];
  const int*   ei   = (const int*)d_in[1];
  const float* ea   = (const float*)d_in[2];
  const float* in_w = (const float*)d_in[3];
  const float* in_b = (const float*)d_in[4];
  const float* Wk   = (const float*)d_in[5];
  const float* bk   = (const float*)d_in[6];
  const float* Wq   = (const float*)d_in[7];
  const float* bq   = (const float*)d_in[8];
  const float* Wv   = (const float*)d_in[9];
  const float* bv   = (const float*)d_in[10];
  const float* We   = (const float*)d_in[11];
  const float* be   = (const float*)d_in[12];
  const float* Ws   = (const float*)d_in[13];
  const float* bs   = (const float*)d_in[14];
  const float* ln_g = (const float*)d_in[15];
  const float* ln_b = (const float*)d_in[16];
  const float* out_w = (const float*)d_in[17];
  float* out = (float*)d_out;

  const int* ei_src = ei;
  const int* ei_dst = ei + Ee;

  size_t NH = (size_t)Nn * Hh;
  char* wsp = (char*)d_ws;
  float*  hA = (float*)wsp;           wsp += NH * 4;
  float*  hB = (float*)wsp;           wsp += NH * 4;
  __half* kb = (__half*)wsp;          wsp += NH * 2;
  __half* qvb = (__half*)wsp;         wsp += NH * 2 * 2;   // [N,256] interleaved q|v
  int* rowptr = (int*)wsp;            wsp += (Nn + 1) * 4;
  int* cursor = (int*)wsp;            wsp += Nn * 4;
  int* bsums  = (int*)wsp;            wsp += 128 * 4;
  int* src_perm = (int*)wsp;          wsp += (size_t)Ee * 4;
  unsigned int* ea_perm = (unsigned int*)wsp; wsp += (size_t)Ee * EDIMM * 4;

  const int NB_SCAN = (Nn + 1023) / 1024;   // 98

  zero_kernel<<<(Nn + 255) / 256, 256, 0, stream>>>(cursor, Nn);
  hist_kernel<<<(Ee + 255) / 256, 256, 0, stream>>>(ei_dst, cursor);
  scan_block_kernel<<<NB_SCAN, 256, 0, stream>>>(cursor, rowptr, bsums);
  scan_sums_kernel<<<1, 128, 0, stream>>>(bsums, NB_SCAN);
  finalize_rowptr_kernel<<<(Nn + 1 + 255) / 256, 256, 0, stream>>>(rowptr, bsums, cursor);
  fill_perm_kernel<<<(Ee + 255) / 256, 256, 0, stream>>>(ei_src, ei_dst, ea, cursor,
                                                         src_perm, ea_perm);

  in_proj_kernel<<<(Nn + 7) / 8, 128, 0, stream>>>(x, in_w, in_b, hA);

  float* h  = hA;
  float* hn = hB;
  for (int l = 0; l < NL; l++) {
    kqvs_kernel<<<(Nn + 7) / 8, 128, 0, stream>>>(h,
        Wk + l * Hh * Hh, bk + l * Hh,
        Wq + l * Hh * Hh, bq + l * Hh,
        Wv + l * Hh * Hh, bv + l * Hh,
        Ws + l * Hh * Hh, bs + l * Hh,
        kb, qvb, hn);
    edge_csr_kernel<<<Nn / 4, 256, 0, stream>>>(kb, qvb, src_perm, ea_perm,
        rowptr, We + l * EDIMM * Hh, be + l * Hh,
        ln_g + l * Hh, ln_b + l * Hh, hn);
    float* tmp = h; h = hn; hn = tmp;
  }

  out_proj_kernel<<<(Nn + 15) / 16, 64, 0, stream>>>(h, out_w, out);
}

// Round 7
// 1789.874 us; speedup vs baseline: 1.5448x; 1.2482x over previous
//
#include <hip/hip_runtime.h>
#include <hip/hip_fp16.h>
#include <cmath>

#define Nn   100000
#define Ee   1600000
#define FIN  256
#define Hh   128
#define EDIMM 16
#define NL   3
#define NOUT 64

typedef _Float16 f16x8 __attribute__((ext_vector_type(8)));
typedef float f32x4 __attribute__((ext_vector_type(4)));

static __device__ __forceinline__ __half2 u2h2(unsigned int u) {
  union { unsigned int u; __half2 h; } c; c.u = u; return c.h;
}
static __device__ __forceinline__ unsigned int h22u(__half2 h) {
  union { unsigned int u; __half2 h; } c; c.h = h; return c.u;
}

// ---------------- in_proj: h = x @ in_w + in_b  [N,256]@[256,128] -> fp16 ----------------
__global__ __launch_bounds__(128) void in_proj_kernel(const float* __restrict__ x,
    const float* __restrict__ w, const float* __restrict__ b, __half* __restrict__ h) {
  __shared__ float xs[8][FIN];
  int r0 = blockIdx.x * 8;
  for (int i = threadIdx.x; i < 8 * FIN; i += 128) {
    int r = i >> 8, c = i & (FIN - 1);
    int rr = r0 + r;
    xs[r][c] = (rr < Nn) ? x[rr * FIN + c] : 0.f;
  }
  __syncthreads();
  int t = threadIdx.x;
  float acc[8] = {};
  for (int kk = 0; kk < FIN; kk++) {
    float wv = w[kk * Hh + t];
#pragma unroll
    for (int r = 0; r < 8; r++) acc[r] += xs[r][kk] * wv;
  }
  float bias = b[t];
#pragma unroll
  for (int r = 0; r < 8; r++) {
    int rr = r0 + r;
    if (rr < Nn) h[rr * Hh + t] = __float2half(acc[r] + bias);
  }
}

// ---- prep: WtT[l][mat][n][k] = W_mat[l][k][n] as fp16 ----
__global__ __launch_bounds__(256) void prep_weights_kernel(const float* __restrict__ Wk,
    const float* __restrict__ Wq, const float* __restrict__ Wv, const float* __restrict__ Ws,
    __half* __restrict__ WtT) {
  int mat = blockIdx.x, l = blockIdx.y;
  const float* W = (mat == 0 ? Wk : mat == 1 ? Wq : mat == 2 ? Wv : Ws) + (size_t)l * Hh * Hh;
  __half* out = WtT + ((size_t)(l * 4 + mat)) * Hh * Hh;
  for (int i = threadIdx.x; i < Hh * Hh; i += 256) {
    int k = i >> 7, n = i & 127;
    out[(size_t)n * Hh + k] = __float2half(W[i]);
  }
}

// ---- MFMA kqvs: grid (4, 3125); block computes 32 rows x 128 cols of one matrix ----
// A[m=lane&15][k=quad*8+j], B[k=quad*8+j][n=lane&15], C col=lane&15 row=quad*4+reg
// (lane mappings HW-validated in round 5)
__global__ __launch_bounds__(256) void kqvs_mfma_kernel(
    const __half* __restrict__ h, const __half* __restrict__ WtT_l,
    const float* __restrict__ bk, const float* __restrict__ bq,
    const float* __restrict__ bv, const float* __restrict__ bs,
    __half* __restrict__ kb, __half* __restrict__ qvj, __half* __restrict__ hnew) {
  __shared__ __half Wl[128][136];
  __shared__ __half Ht[32][136];
  int mat = blockIdx.x;
  int r0 = blockIdx.y * 32;      // 3125*32 = 100000 exactly
  int tid = threadIdx.x;

  const uint4* wg = (const uint4*)(WtT_l + (size_t)mat * Hh * Hh);
  for (int i = tid; i < 2048; i += 256) {
    int rw = i >> 4, cw = i & 15;
    *(uint4*)(&Wl[rw][cw * 8]) = wg[i];
  }
  const uint4* hg = (const uint4*)(h + (size_t)r0 * Hh);
  for (int i = tid; i < 512; i += 256) {
    int rh = i >> 4, ch = i & 15;
    *(uint4*)(&Ht[rh][ch * 8]) = hg[i];
  }
  __syncthreads();

  int wv = tid >> 6, lane = tid & 63;
  int rowHalf = wv & 1, colHalf = wv >> 1;
  int quad = lane >> 4, l16 = lane & 15;

  f32x4 acc[4];
#pragma unroll
  for (int t = 0; t < 4; t++) acc[t] = (f32x4){0.f, 0.f, 0.f, 0.f};

#pragma unroll
  for (int kstep = 0; kstep < 4; kstep++) {
    f16x8 afrag = *(const f16x8*)(&Ht[rowHalf * 16 + l16][kstep * 32 + quad * 8]);
#pragma unroll
    for (int t = 0; t < 4; t++) {
      int n = colHalf * 64 + t * 16 + l16;
      f16x8 bfrag = *(const f16x8*)(&Wl[n][kstep * 32 + quad * 8]);
      acc[t] = __builtin_amdgcn_mfma_f32_16x16x32_f16(afrag, bfrag, acc[t], 0, 0, 0);
    }
  }

  const float* bp = (mat == 0) ? bk : (mat == 1) ? bq : (mat == 2) ? bv : bs;
#pragma unroll
  for (int t = 0; t < 4; t++) {
    int col = colHalf * 64 + t * 16 + l16;
    float bval = bp[col];
#pragma unroll
    for (int r = 0; r < 4; r++) {
      int row = r0 + rowHalf * 16 + quad * 4 + r;
      __half hv = __float2half(acc[t][r] + bval);
      if (mat == 0)       kb[(size_t)row * Hh + col] = hv;
      else if (mat == 1)  qvj[(size_t)row * 256 + (col >> 1) * 4 + (col & 1)] = hv;
      else if (mat == 2)  qvj[(size_t)row * 256 + (col >> 1) * 4 + 2 + (col & 1)] = hv;
      else                hnew[(size_t)row * Hh + col] = hv;
    }
  }
}

// ---------------- CSR build ----------------
__global__ __launch_bounds__(256) void zero_kernel(int* __restrict__ p, int n) {
  int i = blockIdx.x * 256 + threadIdx.x;
  if (i < n) p[i] = 0;
}

__global__ __launch_bounds__(256) void hist_kernel(const int* __restrict__ ei_dst,
                                                   int* __restrict__ counts) {
  int e = blockIdx.x * 256 + threadIdx.x;
  if (e < Ee) atomicAdd(&counts[ei_dst[e]], 1);
}

__global__ __launch_bounds__(256) void scan_block_kernel(const int* __restrict__ counts,
    int* __restrict__ rowptr, int* __restrict__ bsums) {
  __shared__ int tsums[256];
  int b = blockIdx.x, t = threadIdx.x;
  int base = b * 1024 + t * 4;
  int v[4]; int s = 0;
#pragma unroll
  for (int j = 0; j < 4; j++) {
    int idx = base + j;
    v[j] = (idx < Nn) ? counts[idx] : 0;
    s += v[j];
  }
  tsums[t] = s;
  __syncthreads();
  for (int off = 1; off < 256; off <<= 1) {
    int y = (t >= off) ? tsums[t - off] : 0;
    __syncthreads();
    tsums[t] += y;
    __syncthreads();
  }
  int excl = tsums[t] - s;
#pragma unroll
  for (int j = 0; j < 4; j++) {
    int idx = base + j;
    if (idx < Nn) rowptr[idx] = excl;
    excl += v[j];
  }
  if (t == 255) bsums[b] = tsums[255];
}

__global__ __launch_bounds__(128) void scan_sums_kernel(int* __restrict__ bsums, int nb) {
  __shared__ int sh[128];
  int t = threadIdx.x;
  int v = (t < nb) ? bsums[t] : 0;
  sh[t] = v;
  __syncthreads();
  for (int off = 1; off < 128; off <<= 1) {
    int y = (t >= off) ? sh[t - off] : 0;
    __syncthreads();
    sh[t] += y;
    __syncthreads();
  }
  if (t < nb) bsums[t] = sh[t] - v;
}

__global__ __launch_bounds__(256) void finalize_rowptr_kernel(int* __restrict__ rowptr,
    const int* __restrict__ bsums, int* __restrict__ cursor) {
  int i = blockIdx.x * 256 + threadIdx.x;
  if (i < Nn) {
    int r = rowptr[i] + bsums[i >> 10];
    rowptr[i] = r;
    cursor[i] = r;
  }
  if (i == Nn) rowptr[Nn] = Ee;
}

// permute: src_perm (int), ea_perm = pre-broadcast half2 (16 uints/edge, 64 B)
__global__ __launch_bounds__(256) void fill_perm_kernel(const int* __restrict__ ei_src,
    const int* __restrict__ ei_dst, const float* __restrict__ ea,
    int* __restrict__ cursor, int* __restrict__ src_perm,
    unsigned int* __restrict__ ea_perm) {
  int e = blockIdx.x * 256 + threadIdx.x;
  if (e < Ee) {
    int d = ei_dst[e];
    int slot = atomicAdd(&cursor[d], 1);
    src_perm[slot] = ei_src[e];
    const float4* s = (const float4*)(ea + (size_t)e * EDIMM);
    float4 f[4] = { s[0], s[1], s[2], s[3] };
    unsigned int u[16];
#pragma unroll
    for (int j = 0; j < 4; j++) {
      u[j*4+0] = h22u(__half2half2(__float2half(f[j].x)));
      u[j*4+1] = h22u(__half2half2(__float2half(f[j].y)));
      u[j*4+2] = h22u(__half2half2(__float2half(f[j].z)));
      u[j*4+3] = h22u(__half2half2(__float2half(f[j].w)));
    }
    uint4* dp = (uint4*)(ea_perm + (size_t)slot * EDIMM);
#pragma unroll
    for (int j = 0; j < 4; j++)
      dp[j] = make_uint4(u[j*4+0], u[j*4+1], u[j*4+2], u[j*4+3]);
  }
}

// ---- CSR edge kernel: one wave per dst row, packed-fp16 math, 8B qv gathers ----
__global__ __launch_bounds__(256, 4) void edge_csr_kernel(
    const __half* __restrict__ kb, const __half* __restrict__ qvj,
    const int* __restrict__ src_perm, const unsigned int* __restrict__ ea_perm,
    const int* __restrict__ rowptr,
    const float* __restrict__ We_l, const float* __restrict__ be_l,
    const float* __restrict__ ln_g_l, const float* __restrict__ ln_b_l,
    __half* __restrict__ hbuf) {
  int wave = threadIdx.x >> 6;
  int lane = threadIdx.x & 63;
  int row = blockIdx.x * 4 + wave;   // grid 25000*4 = 100000 exactly
  int c0 = lane * 2;

  __half2 wpk[EDIMM];
#pragma unroll
  for (int d = 0; d < EDIMM; d++) {
    float2 wv = *(const float2*)(We_l + d * Hh + c0);
    wpk[d] = __floats2half2_rn(wv.x, wv.y);
  }
  float2 bef = *(const float2*)(be_l + c0);
  __half2 bev = __floats2half2_rn(bef.x, bef.y);

  __half2 kpk = *(const __half2*)(kb + (size_t)row * Hh + c0);

  float agg0 = 0.f, agg1 = 0.f;
  int beg = rowptr[row], end = rowptr[row + 1];

  auto edge_math = [&](uint4 a2, uint4 a3, uint4 a0, uint4 a1, uint2 qv) {
    __half2 qh = u2h2(qv.x), vh = u2h2(qv.y);
    __half2 acc = bev;
    acc = __hfma2(u2h2(a0.x), wpk[0],  acc);
    acc = __hfma2(u2h2(a0.y), wpk[1],  acc);
    acc = __hfma2(u2h2(a0.z), wpk[2],  acc);
    acc = __hfma2(u2h2(a0.w), wpk[3],  acc);
    acc = __hfma2(u2h2(a1.x), wpk[4],  acc);
    acc = __hfma2(u2h2(a1.y), wpk[5],  acc);
    acc = __hfma2(u2h2(a1.z), wpk[6],  acc);
    acc = __hfma2(u2h2(a1.w), wpk[7],  acc);
    acc = __hfma2(u2h2(a2.x), wpk[8],  acc);
    acc = __hfma2(u2h2(a2.y), wpk[9],  acc);
    acc = __hfma2(u2h2(a2.z), wpk[10], acc);
    acc = __hfma2(u2h2(a2.w), wpk[11], acc);
    acc = __hfma2(u2h2(a3.x), wpk[12], acc);
    acc = __hfma2(u2h2(a3.y), wpk[13], acc);
    acc = __hfma2(u2h2(a3.z), wpk[14], acc);
    acc = __hfma2(u2h2(a3.w), wpk[15], acc);
    __half2 pre = __hadd2(__hadd2(kpk, qh), acc);
    float p0 = __half2float(__low2half(pre));
    float p1 = __half2float(__high2half(pre));
    float g0 = 1.f / (1.f + __expf(-p0));
    float g1 = 1.f / (1.f + __expf(-p1));
    agg0 += g0 * __half2float(__low2half(vh));
    agg1 += g1 * __half2float(__high2half(vh));
  };

  int e = beg;
  for (; e + 4 <= end; e += 4) {
    int4 s4 = *(const int4*)(src_perm + e);
    // ---- hoist ALL batch loads before any compute ----
    const uint4* eb = (const uint4*)(ea_perm + (size_t)e * EDIMM);
    uint4 ea0a = eb[0], ea0b = eb[1], ea0c = eb[2], ea0d = eb[3];
    uint4 ea1a = eb[4], ea1b = eb[5], ea1c = eb[6], ea1d = eb[7];
    uint2 qv0 = *(const uint2*)(qvj + (size_t)s4.x * 256 + (lane << 2));
    uint2 qv1 = *(const uint2*)(qvj + (size_t)s4.y * 256 + (lane << 2));
    uint2 qv2 = *(const uint2*)(qvj + (size_t)s4.z * 256 + (lane << 2));
    uint2 qv3 = *(const uint2*)(qvj + (size_t)s4.w * 256 + (lane << 2));
    uint4 ea2a = eb[8],  ea2b = eb[9],  ea2c = eb[10], ea2d = eb[11];
    uint4 ea3a = eb[12], ea3b = eb[13], ea3c = eb[14], ea3d = eb[15];
    // ---- compute ----
    edge_math(ea0c, ea0d, ea0a, ea0b, qv0);
    edge_math(ea1c, ea1d, ea1a, ea1b, qv1);
    edge_math(ea2c, ea2d, ea2a, ea2b, qv2);
    edge_math(ea3c, ea3d, ea3a, ea3b, qv3);
  }
  for (; e < end; e++) {
    int src = src_perm[e];
    const uint4* eb = (const uint4*)(ea_perm + (size_t)e * EDIMM);
    uint4 a0 = eb[0], a1 = eb[1], a2 = eb[2], a3 = eb[3];
    uint2 qv = *(const uint2*)(qvj + (size_t)src * 256 + (lane << 2));
    edge_math(a2, a3, a0, a1, qv);
  }

  // skip + LayerNorm + GELU (wave owns full row: 2 channels/lane)
  __half2 hv2 = *(const __half2*)(hbuf + (size_t)row * Hh + c0);
  float y0 = __half2float(hv2.x) + agg0, y1 = __half2float(hv2.y) + agg1;
  float s = y0 + y1;
#pragma unroll
  for (int off = 32; off; off >>= 1) s += __shfl_xor(s, off);
  float mu = s * (1.f / 128.f);
  float d0 = y0 - mu, d1 = y1 - mu;
  float vv = d0 * d0 + d1 * d1;
#pragma unroll
  for (int off = 32; off; off >>= 1) vv += __shfl_xor(vv, off);
  float rstd = rsqrtf(vv * (1.f / 128.f) + 1e-5f);
  float2 lg = *(const float2*)(ln_g_l + c0);
  float2 lb = *(const float2*)(ln_b_l + c0);
  float o0 = d0 * rstd * lg.x + lb.x;
  float o1 = d1 * rstd * lg.y + lb.y;
  o0 = 0.5f * o0 * (1.f + erff(o0 * 0.70710678118654752f));
  o1 = 0.5f * o1 * (1.f + erff(o1 * 0.70710678118654752f));
  *(__half2*)(hbuf + (size_t)row * Hh + c0) = __floats2half2_rn(o0, o1);
}

// ---- out_proj: out = h @ out_w  [N,128]@[128,64], h fp16 ----
__global__ __launch_bounds__(64) void out_proj_kernel(const __half* __restrict__ h,
    const float* __restrict__ w, float* __restrict__ out) {
  __shared__ float hs[16][Hh];
  int r0 = blockIdx.x * 16;    // 6250*16 = 100000 exactly
  const uint4* hg = (const uint4*)(h + (size_t)r0 * Hh);
  for (int i = threadIdx.x; i < 256; i += 64) {
    uint4 u = hg[i];
    int r = i >> 4, c = (i & 15) * 8;
    __half2 ha = u2h2(u.x), hb = u2h2(u.y), hc = u2h2(u.z), hd = u2h2(u.w);
    hs[r][c+0] = __half2float(ha.x); hs[r][c+1] = __half2float(ha.y);
    hs[r][c+2] = __half2float(hb.x); hs[r][c+3] = __half2float(hb.y);
    hs[r][c+4] = __half2float(hc.x); hs[r][c+5] = __half2float(hc.y);
    hs[r][c+6] = __half2float(hd.x); hs[r][c+7] = __half2float(hd.y);
  }
  __syncthreads();
  int t = threadIdx.x;
  float acc[16] = {};
  for (int kk = 0; kk < Hh; kk++) {
    float wv = w[kk * NOUT + t];
#pragma unroll
    for (int r = 0; r < 16; r++) acc[r] += hs[r][kk] * wv;
  }
#pragma unroll
  for (int r = 0; r < 16; r++) out[(size_t)(r0 + r) * NOUT + t] = acc[r];
}

extern "C" void kernel_launch(void* const* d_in, const int* in_sizes, int n_in,
                              void* d_out, int out_size, void* d_ws, size_t ws_size,
                              hipStream_t stream) {
  const float* x    = (const float*)d_in[0];
  const int*   ei   = (const int*)d_in[1];
  const float* ea   = (const float*)d_in[2];
  const float* in_w = (const float*)d_in[3];
  const float* in_b = (const float*)d_in[4];
  const float* Wk   = (const float*)d_in[5];
  const float* bk   = (const float*)d_in[6];
  const float* Wq   = (const float*)d_in[7];
  const float* bq   = (const float*)d_in[8];
  const float* Wv   = (const float*)d_in[9];
  const float* bv   = (const float*)d_in[10];
  const float* We   = (const float*)d_in[11];
  const float* be   = (const float*)d_in[12];
  const float* Ws   = (const float*)d_in[13];
  const float* bs   = (const float*)d_in[14];
  const float* ln_g = (const float*)d_in[15];
  const float* ln_b = (const float*)d_in[16];
  const float* out_w = (const float*)d_in[17];
  float* out = (float*)d_out;

  const int* ei_src = ei;
  const int* ei_dst = ei + Ee;

  size_t NH = (size_t)Nn * Hh;
  char* wsp = (char*)d_ws;
  __half* hA = (__half*)wsp;          wsp += NH * 2;
  __half* hB = (__half*)wsp;          wsp += NH * 2;
  __half* kb = (__half*)wsp;          wsp += NH * 2;
  __half* qvj = (__half*)wsp;         wsp += NH * 2 * 2;   // [N,256] pair-interleaved q|v
  __half* WtT = (__half*)wsp;         wsp += (size_t)NL * 4 * Hh * Hh * 2;
  int* rowptr = (int*)wsp;            wsp += (Nn + 1) * 4;
  int* cursor = (int*)wsp;            wsp += Nn * 4;
  int* bsums  = (int*)wsp;            wsp += 128 * 4;
  int* src_perm = (int*)wsp;          wsp += (size_t)Ee * 4;
  unsigned int* ea_perm = (unsigned int*)wsp; wsp += (size_t)Ee * EDIMM * 4;

  const int NB_SCAN = (Nn + 1023) / 1024;   // 98

  zero_kernel<<<(Nn + 255) / 256, 256, 0, stream>>>(cursor, Nn);
  hist_kernel<<<(Ee + 255) / 256, 256, 0, stream>>>(ei_dst, cursor);
  scan_block_kernel<<<NB_SCAN, 256, 0, stream>>>(cursor, rowptr, bsums);
  scan_sums_kernel<<<1, 128, 0, stream>>>(bsums, NB_SCAN);
  finalize_rowptr_kernel<<<(Nn + 1 + 255) / 256, 256, 0, stream>>>(rowptr, bsums, cursor);
  fill_perm_kernel<<<(Ee + 255) / 256, 256, 0, stream>>>(ei_src, ei_dst, ea, cursor,
                                                         src_perm, ea_perm);
  prep_weights_kernel<<<dim3(4, NL), 256, 0, stream>>>(Wk, Wq, Wv, Ws, WtT);

  in_proj_kernel<<<(Nn + 7) / 8, 128, 0, stream>>>(x, in_w, in_b, hA);

  __half* h  = hA;
  __half* hn = hB;
  for (int l = 0; l < NL; l++) {
    kqvs_mfma_kernel<<<dim3(4, Nn / 32), 256, 0, stream>>>(h,
        WtT + (size_t)l * 4 * Hh * Hh,
        bk + l * Hh, bq + l * Hh, bv + l * Hh, bs + l * Hh,
        kb, qvj, hn);
    edge_csr_kernel<<<Nn / 4, 256, 0, stream>>>(kb, qvj, src_perm, ea_perm,
        rowptr, We + l * EDIMM * Hh, be + l * Hh,
        ln_g + l * Hh, ln_b + l * Hh, hn);
    __half* tmp = h; h = hn; hn = tmp;
  }

  out_proj_kernel<<<Nn / 16, 64, 0, stream>>>(h, out_w, out);
}